// Round 15
// baseline (450.541 us; speedup 1.0000x reference)
//
#include <hip/hip_runtime.h>
#include <hip/hip_bf16.h>

#define N_NODES 4000
#define N_EDGES 4000
#define T_ALL   8000
#define HID     768

typedef __attribute__((ext_vector_type(8))) short bf16x8;
typedef __attribute__((ext_vector_type(4))) short s16x4;
typedef __attribute__((ext_vector_type(4))) float f32x4;

__device__ __forceinline__ short f2bf(float f) {
    union { float f; unsigned u; } a; a.f = f;
    unsigned u = a.u;
    unsigned r = (u + 0x7fffu + ((u >> 16) & 1u)) >> 16;   // RNE
    return (short)(r & 0xffffu);
}
__device__ __forceinline__ float bf2f(short s) {
    union { unsigned u; float f; } a;
    a.u = ((unsigned)(unsigned short)s) << 16;
    return a.f;
}
__device__ __forceinline__ void gload_lds16(const void* g, void* l) {
    __builtin_amdgcn_global_load_lds(
        (const __attribute__((address_space(1))) void*)g,
        (__attribute__((address_space(3))) void*)l, 16, 0, 0);
}

// ===== big GEMM: 256x256, K32-tile ring-4, reg-lookahead, A from F32 =======
// parts[z][M,768] = bf16(A_f32)[M,kslice] * BT[768,kslice]^T
// A staged via reg (4x float4 -> 16 f2bf -> 2 swizzled ds_write_b128);
// B staged via global_load_lds. Manual vmcnt counts B-loads only (2/tile):
// prologue vmcnt(4); steady vmcnt(2); tail vmcnt(0). lgkmcnt(0) before each
// tile-end barrier publishes A ds_writes cross-wave.
__global__ __launch_bounds__(512, 2) void gemm_ring(
    const float* __restrict__ A, const short* __restrict__ BT,
    short* __restrict__ parts, int M, int K, int lda, int ldbt)
{
    __shared__ __align__(16) short As[4][256 * 32];
    __shared__ __align__(16) short Bs[4][256 * 32];
    const int t    = threadIdx.x;
    const int lane = t & 63;
    const int wv   = t >> 6;
    const int wm   = wv >> 2;
    const int wn   = wv & 3;
    const int lrow = lane & 15;
    const int kgrp = lane >> 4;

    const int nwg  = gridDim.x * gridDim.y * gridDim.z;
    int flat = blockIdx.x + gridDim.x * (blockIdx.y + gridDim.y * blockIdx.z);
    int w    = (flat & 7) * (nwg >> 3) + (flat >> 3);
    const int bx = w % 3;
    int rest = w / 3;
    const int by = rest & 31;
    const int bz = rest >> 5;
    const int bm0 = by << 8;
    const int bn0 = bx << 8;

    const int TC = K >> 5;
    const int Z  = gridDim.z;
    const int q  = TC / Z, r = TC % Z;
    const int nt   = q + (bz < r ? 1 : 0);
    const int kbeg = ((bz < r) ? bz * (q + 1) : r * (q + 1) + (bz - r) * q) << 5;

    // A: thread covers row = t>>1, 16 f32 at k-offset (t&1)*16
    const int arow = t >> 1;
    const int kh   = (t & 1) << 4;
    const int aswz = (arow >> 1) & 3;
    const int sl0  = kh >> 3;               // 0 or 2

    auto stageA = [&](int tt) {
        const int k0 = kbeg + (tt << 5);
        short* dst = &As[tt & 3][arow << 5];
        int ga = bm0 + arow; ga = ga < M ? ga : M - 1;
        const float* ap = A + (size_t)ga * lda + k0 + kh;
        {
            float4 v0 = *reinterpret_cast<const float4*>(ap);
            float4 v1 = *reinterpret_cast<const float4*>(ap + 4);
            union { bf16x8 v; short s[8]; } u;
            u.s[0] = f2bf(v0.x); u.s[1] = f2bf(v0.y); u.s[2] = f2bf(v0.z); u.s[3] = f2bf(v0.w);
            u.s[4] = f2bf(v1.x); u.s[5] = f2bf(v1.y); u.s[6] = f2bf(v1.z); u.s[7] = f2bf(v1.w);
            *reinterpret_cast<bf16x8*>(&dst[(sl0 ^ aswz) << 3]) = u.v;
        }
        {
            float4 v2 = *reinterpret_cast<const float4*>(ap + 8);
            float4 v3 = *reinterpret_cast<const float4*>(ap + 12);
            union { bf16x8 v; short s[8]; } u;
            u.s[0] = f2bf(v2.x); u.s[1] = f2bf(v2.y); u.s[2] = f2bf(v2.z); u.s[3] = f2bf(v2.w);
            u.s[4] = f2bf(v3.x); u.s[5] = f2bf(v3.y); u.s[6] = f2bf(v3.z); u.s[7] = f2bf(v3.w);
            *reinterpret_cast<bf16x8*>(&dst[((sl0 + 1) ^ aswz) << 3]) = u.v;
        }
    };
    auto stageB = [&](int tt) {
        const int k0 = kbeg + (tt << 5);
        short* dst = &Bs[tt & 3][0];
#pragma unroll
        for (int i = 0; i < 2; ++i) {
            int f = t + (i << 9);
            int row = f >> 2, sl = f & 3;
            gload_lds16(BT + (size_t)(bn0 + row) * ldbt + k0 + ((sl ^ ((row >> 1) & 3)) << 3),
                        dst + f * 8);
        }
    };

    f32x4 acc[8][4];
#pragma unroll
    for (int m = 0; m < 8; ++m)
#pragma unroll
        for (int n = 0; n < 4; ++n) acc[m][n] = (f32x4)(0.0f);

    stageB(0); stageA(0);
    stageB(1); stageA(1);
    stageB(2); stageA(2);
    asm volatile("s_waitcnt vmcnt(4)" ::: "memory");
    asm volatile("s_waitcnt lgkmcnt(0)" ::: "memory");
    __builtin_amdgcn_s_barrier();

    bf16x8 r0A0[4], r0A1[4], r0B[4];
    bf16x8 r1A0[4], r1A1[4], r1B[4];

    {
        const short* Ac = &As[0][0];
        const short* Bc = &Bs[0][0];
#pragma unroll
        for (int m = 0; m < 4; ++m) {
            int rr = (wm << 7) + (m << 4) + lrow;
            r0A0[m] = *reinterpret_cast<const bf16x8*>(
                &Ac[(rr << 5) + ((kgrp ^ ((rr >> 1) & 3)) << 3)]);
        }
#pragma unroll
        for (int n = 0; n < 4; ++n) {
            int rr = (wn << 6) + (n << 4) + lrow;
            r0B[n] = *reinterpret_cast<const bf16x8*>(
                &Bc[(rr << 5) + ((kgrp ^ ((rr >> 1) & 3)) << 3)]);
        }
#pragma unroll
        for (int m = 0; m < 4; ++m) {
            int rr = (wm << 7) + 64 + (m << 4) + lrow;
            r0A1[m] = *reinterpret_cast<const bf16x8*>(
                &Ac[(rr << 5) + ((kgrp ^ ((rr >> 1) & 3)) << 3)]);
        }
    }

#define TILE_STEP(TT, cA0, cA1, cB, nA0, nA1, nB)                              \
    {                                                                          \
        const int _tt = (TT);                                                  \
        if (_tt + 1 < nt) {                                                    \
            const short* An = &As[(_tt + 1) & 3][0];                           \
            const short* Bn = &Bs[(_tt + 1) & 3][0];                           \
            _Pragma("unroll")                                                  \
            for (int m = 0; m < 4; ++m) {                                      \
                int rr = (wm << 7) + (m << 4) + lrow;                          \
                nA0[m] = *reinterpret_cast<const bf16x8*>(                     \
                    &An[(rr << 5) + ((kgrp ^ ((rr >> 1) & 3)) << 3)]);         \
            }                                                                  \
            _Pragma("unroll")                                                  \
            for (int n = 0; n < 4; ++n) {                                      \
                int rr = (wn << 6) + (n << 4) + lrow;                          \
                nB[n] = *reinterpret_cast<const bf16x8*>(                      \
                    &Bn[(rr << 5) + ((kgrp ^ ((rr >> 1) & 3)) << 3)]);         \
            }                                                                  \
            _Pragma("unroll")                                                  \
            for (int m = 0; m < 4; ++m) {                                      \
                int rr = (wm << 7) + 64 + (m << 4) + lrow;                     \
                nA1[m] = *reinterpret_cast<const bf16x8*>(                     \
                    &An[(rr << 5) + ((kgrp ^ ((rr >> 1) & 3)) << 3)]);         \
            }                                                                  \
        }                                                                      \
        if (_tt + 3 < nt) { stageB(_tt + 3); stageA(_tt + 3); }                \
        __builtin_amdgcn_sched_barrier(0);                                     \
        __builtin_amdgcn_s_setprio(1);                                         \
        _Pragma("unroll")                                                      \
        for (int m = 0; m < 4; ++m)                                            \
            _Pragma("unroll")                                                  \
            for (int n = 0; n < 4; ++n)                                        \
                acc[m][n] = __builtin_amdgcn_mfma_f32_16x16x32_bf16(           \
                    cA0[m], cB[n], acc[m][n], 0, 0, 0);                        \
        _Pragma("unroll")                                                      \
        for (int m = 0; m < 4; ++m)                                            \
            _Pragma("unroll")                                                  \
            for (int n = 0; n < 4; ++n)                                        \
                acc[4 + m][n] = __builtin_amdgcn_mfma_f32_16x16x32_bf16(       \
                    cA1[m], cB[n], acc[4 + m][n], 0, 0, 0);                    \
        __builtin_amdgcn_s_setprio(0);                                         \
        if (_tt <= nt - 4) asm volatile("s_waitcnt vmcnt(2)" ::: "memory");    \
        else               asm volatile("s_waitcnt vmcnt(0)" ::: "memory");    \
        asm volatile("s_waitcnt lgkmcnt(0)" ::: "memory");                     \
        __builtin_amdgcn_s_barrier();                                          \
    }

    int tt = 0;
    for (; tt + 1 < nt; tt += 2) {
        TILE_STEP(tt,     r0A0, r0A1, r0B, r1A0, r1A1, r1B);
        TILE_STEP(tt + 1, r1A0, r1A1, r1B, r0A0, r0A1, r0B);
    }
    if (tt < nt) TILE_STEP(tt, r0A0, r0A1, r0B, r1A0, r1A1, r1B);
#undef TILE_STEP

    short* Cp = parts + (size_t)bz * 6144000;
#pragma unroll
    for (int m = 0; m < 8; ++m) {
        int r0 = bm0 + (wm << 7) + (m << 4) + (kgrp << 2);
#pragma unroll
        for (int n = 0; n < 4; ++n) {
            int col = bn0 + (wn << 6) + (n << 4) + lrow;
#pragma unroll
            for (int j = 0; j < 4; ++j) {
                int rr = r0 + j;
                if (rr < M) Cp[(size_t)rr * 768 + col] = f2bf(acc[m][n][j]);
            }
        }
    }
}

// ---------------- GEMM: C[M,N] = A[M,K] * B  (B given as BT[N,K], bf16) ----
// GAT=1: B rows indirected via srcmap (fused gather).
template<int BIAS, int RELU, int OUTBF, int AF32, int GAT>
__global__ __launch_bounds__(256) void gemm_bf(
    const void* __restrict__ Av, const short* __restrict__ BT,
    const float* __restrict__ bias, void* __restrict__ Cv,
    int M, int N, int K, int lda, int ldbt, int ldc,
    const int* __restrict__ srcmap)
{
    __shared__ __align__(16) short As[2][128 * 64];
    __shared__ __align__(16) short Bs[2][128 * 64];
    const int t    = threadIdx.x;
    const int lane = t & 63;
    const int wave = t >> 6;
    const int wr   = (wave >> 1) << 6;
    const int wc   = (wave & 1) << 6;
    const int lrow = lane & 15;
    const int kgrp = lane >> 4;
    const int bm0  = blockIdx.y << 7;
    const int bn0  = blockIdx.x << 7;
    const short* Ab = (const short*)Av;
    const float* Af = (const float*)Av;

    const int nk = K >> 6;

    auto stage = [&](int kt, int buf) {
        const int k0 = kt << 6;
#pragma unroll
        for (int i = 0; i < 4; ++i) {
            int f = t + (i << 8);
            int row = f >> 3, slot = f & 7;
            int gb = bn0 + row; gb = (gb < N) ? gb : (N - 1);
            int sr = GAT ? srcmap[gb] : gb;
            gload_lds16(BT + (size_t)sr * ldbt + k0 + ((slot ^ (row & 7)) << 3),
                        &Bs[buf][((i << 8) + (wave << 6)) * 8]);
        }
        if constexpr (!AF32) {
#pragma unroll
            for (int i = 0; i < 4; ++i) {
                int f = t + (i << 8);
                int row = f >> 3, slot = f & 7;
                int ga = bm0 + row; ga = (ga < M) ? ga : (M - 1);
                gload_lds16(Ab + (size_t)ga * lda + k0 + ((slot ^ (row & 7)) << 3),
                            &As[buf][((i << 8) + (wave << 6)) * 8]);
            }
        } else {
#pragma unroll
            for (int i = 0; i < 4; ++i) {
                int f = t + (i << 8);
                int row = f >> 3, c8 = f & 7;
                int ga = bm0 + row; ga = (ga < M) ? ga : (M - 1);
                const float* ap = Af + (size_t)ga * lda + k0 + (c8 << 3);
                float4 v0 = *reinterpret_cast<const float4*>(ap);
                float4 v1 = *reinterpret_cast<const float4*>(ap + 4);
                union { bf16x8 v; short s[8]; } u;
                u.s[0] = f2bf(v0.x); u.s[1] = f2bf(v0.y); u.s[2] = f2bf(v0.z); u.s[3] = f2bf(v0.w);
                u.s[4] = f2bf(v1.x); u.s[5] = f2bf(v1.y); u.s[6] = f2bf(v1.z); u.s[7] = f2bf(v1.w);
                *reinterpret_cast<bf16x8*>(&As[buf][row * 64 + ((c8 ^ (row & 7)) << 3)]) = u.v;
            }
        }
    };

    f32x4 acc[4][4];
#pragma unroll
    for (int m = 0; m < 4; ++m)
#pragma unroll
        for (int n = 0; n < 4; ++n) acc[m][n] = (f32x4)(0.0f);

    auto compute = [&](int buf) {
#pragma unroll
        for (int kk = 0; kk < 2; ++kk) {
            bf16x8 af[4], bfv[4];
#pragma unroll
            for (int m = 0; m < 4; ++m) {
                int rr = wr + m * 16 + lrow;
                af[m] = *reinterpret_cast<const bf16x8*>(
                    &As[buf][rr * 64 + (((kk * 4 + kgrp) ^ (rr & 7)) << 3)]);
            }
#pragma unroll
            for (int n = 0; n < 4; ++n) {
                int rr = wc + n * 16 + lrow;
                bfv[n] = *reinterpret_cast<const bf16x8*>(
                    &Bs[buf][rr * 64 + (((kk * 4 + kgrp) ^ (rr & 7)) << 3)]);
            }
#pragma unroll
            for (int m = 0; m < 4; ++m)
#pragma unroll
                for (int n = 0; n < 4; ++n)
                    acc[m][n] = __builtin_amdgcn_mfma_f32_16x16x32_bf16(
                        af[m], bfv[n], acc[m][n], 0, 0, 0);
        }
    };

    if constexpr (!AF32) {
        stage(0, 0);
        if (nk > 1) stage(1, 1);
        for (int kt = 0; kt < nk - 1; ++kt) {
            asm volatile("s_waitcnt vmcnt(8)" ::: "memory");
            __builtin_amdgcn_s_barrier();
            compute(kt & 1);
            __builtin_amdgcn_s_barrier();
            if (kt + 2 < nk) stage(kt + 2, kt & 1);
        }
        asm volatile("s_waitcnt vmcnt(0)" ::: "memory");
        __builtin_amdgcn_s_barrier();
        compute((nk - 1) & 1);
    } else {
        stage(0, 0);
        __syncthreads();
        int cur = 0;
        for (int kt = 0; kt < nk; ++kt) {
            if (kt + 1 < nk) stage(kt + 1, cur ^ 1);
            compute(cur);
            __syncthreads();
            cur ^= 1;
        }
    }

    short* Cb = (short*)Cv;
    float* Cf = (float*)Cv;
#pragma unroll
    for (int m = 0; m < 4; ++m) {
        int rbase = bm0 + wr + m * 16 + kgrp * 4;
#pragma unroll
        for (int n = 0; n < 4; ++n) {
            int col = bn0 + wc + n * 16 + lrow;
            if (col >= N) continue;
            float bv = BIAS ? bias[col] : 0.0f;
#pragma unroll
            for (int j = 0; j < 4; ++j) {
                int rr = rbase + j;
                if (rr < M) {
                    float v = acc[m][n][j] + bv;
                    if (RELU) v = fmaxf(v, 0.0f);
                    if (OUTBF) Cb[(size_t)rr * ldc + col] = f2bf(v);
                    else       Cf[(size_t)rr * ldc + col] = v;
                }
            }
        }
    }
}

// ---- stacked-M MLP GEMM: M=8192 (edge rows 0.., node rows 4096..), N=768 ---
template<int RELU>
__global__ __launch_bounds__(256) void gemm_sel(
    const short* __restrict__ A,
    const short* __restrict__ BT1, const short* __restrict__ BT2,
    const float* __restrict__ bias1, const float* __restrict__ bias2,
    short* __restrict__ C, int K)
{
    __shared__ __align__(16) short As[2][128 * 64];
    __shared__ __align__(16) short Bs[2][128 * 64];
    const int t    = threadIdx.x;
    const int lane = t & 63;
    const int wave = t >> 6;
    const int wr   = (wave >> 1) << 6;
    const int wc   = (wave & 1) << 6;
    const int lrow = lane & 15;
    const int kgrp = lane >> 4;
    const int bm0  = blockIdx.y << 7;
    const int bn0  = blockIdx.x << 7;
    const short* BT   = (bm0 < 4096) ? BT1 : BT2;
    const float* bias = (bm0 < 4096) ? bias1 : bias2;
    const int nk = K >> 6;

    auto stage = [&](int kt, int buf) {
        const int k0 = kt << 6;
#pragma unroll
        for (int i = 0; i < 4; ++i) {
            int f = t + (i << 8);
            int row = f >> 3, slot = f & 7;
            gload_lds16(BT + (size_t)(bn0 + row) * K + k0 + ((slot ^ (row & 7)) << 3),
                        &Bs[buf][((i << 8) + (wave << 6)) * 8]);
        }
#pragma unroll
        for (int i = 0; i < 4; ++i) {
            int f = t + (i << 8);
            int row = f >> 3, slot = f & 7;
            gload_lds16(A + (size_t)(bm0 + row) * K + k0 + ((slot ^ (row & 7)) << 3),
                        &As[buf][((i << 8) + (wave << 6)) * 8]);
        }
    };

    f32x4 acc[4][4];
#pragma unroll
    for (int m = 0; m < 4; ++m)
#pragma unroll
        for (int n = 0; n < 4; ++n) acc[m][n] = (f32x4)(0.0f);

    auto compute = [&](int buf) {
#pragma unroll
        for (int kk = 0; kk < 2; ++kk) {
            bf16x8 af[4], bfv[4];
#pragma unroll
            for (int m = 0; m < 4; ++m) {
                int rr = wr + m * 16 + lrow;
                af[m] = *reinterpret_cast<const bf16x8*>(
                    &As[buf][rr * 64 + (((kk * 4 + kgrp) ^ (rr & 7)) << 3)]);
            }
#pragma unroll
            for (int n = 0; n < 4; ++n) {
                int rr = wc + n * 16 + lrow;
                bfv[n] = *reinterpret_cast<const bf16x8*>(
                    &Bs[buf][rr * 64 + (((kk * 4 + kgrp) ^ (rr & 7)) << 3)]);
            }
#pragma unroll
            for (int m = 0; m < 4; ++m)
#pragma unroll
                for (int n = 0; n < 4; ++n)
                    acc[m][n] = __builtin_amdgcn_mfma_f32_16x16x32_bf16(
                        af[m], bfv[n], acc[m][n], 0, 0, 0);
        }
    };

    stage(0, 0);
    if (nk > 1) stage(1, 1);
    for (int kt = 0; kt < nk - 1; ++kt) {
        asm volatile("s_waitcnt vmcnt(8)" ::: "memory");
        __builtin_amdgcn_s_barrier();
        compute(kt & 1);
        __builtin_amdgcn_s_barrier();
        if (kt + 2 < nk) stage(kt + 2, kt & 1);
    }
    asm volatile("s_waitcnt vmcnt(0)" ::: "memory");
    __builtin_amdgcn_s_barrier();
    compute((nk - 1) & 1);

#pragma unroll
    for (int m = 0; m < 4; ++m) {
        int rbase = bm0 + wr + m * 16 + kgrp * 4;
#pragma unroll
        for (int n = 0; n < 4; ++n) {
            int col = bn0 + wc + n * 16 + lrow;
            float bv = bias[col];
#pragma unroll
            for (int j = 0; j < 4; ++j) {
                float v = acc[m][n][j] + bv;
                if (RELU) v = fmaxf(v, 0.0f);
                C[(size_t)(rbase + j) * 768 + col] = f2bf(v);
            }
        }
    }
}

// ====== prep_all: transposes + edge rows + node pad + build_src =============
// build_src emits F2s ROW INDEX directly: edge -> row e, node -> 4096+n
__global__ __launch_bounds__(256) void prep_all(
    const float* __restrict__ data, const int* __restrict__ trans,
    const float* __restrict__ w1, const float* __restrict__ w2,
    const float* __restrict__ w21, const float* __restrict__ w22,
    const float* __restrict__ gw1, const int* __restrict__ einx,
    short* __restrict__ w1T, short* __restrict__ w2T,
    short* __restrict__ w21T, short* __restrict__ w22T,
    short* __restrict__ gw1T, short* __restrict__ estack,
    int* __restrict__ src)
{
    __shared__ float tile[32][33];
    __shared__ int ibuf[512];
    const int blk = blockIdx.x, tid = threadIdx.x;

    if (blk < 2496) {
        if (blk < 384) {
            int i = blk * 256 + tid, n = i >> 7, k = i & 127;
            w1T[i] = (k < 120) ? f2bf(w1[k * 768 + n]) : (short)0;
        } else if (blk < 1344) {
            if (blk < 960) {
                int j = blk - 384, bx = j % 24, by = j / 24;
                int c0 = bx << 5, r0 = by << 5, tx = tid & 31, ty = tid >> 5;
#pragma unroll
                for (int i = ty; i < 32; i += 8)
                    tile[i][tx] = w2[(size_t)(r0 + i) * 768 + c0 + tx];
                __syncthreads();
#pragma unroll
                for (int i = ty; i < 32; i += 8)
                    w2T[(size_t)(c0 + i) * 768 + r0 + tx] = f2bf(tile[tx][i]);
            } else {
                int i = (blk - 960) * 256 + tid, n = i >> 7, k = i & 127;
                w21T[i] = (k < 20) ? f2bf(w21[k * 768 + n]) : (short)0;
            }
        } else if (blk < 1920) {
            int j = blk - 1344, bx = j % 24, by = j / 24;
            int c0 = bx << 5, r0 = by << 5, tx = tid & 31, ty = tid >> 5;
#pragma unroll
            for (int i = ty; i < 32; i += 8)
                tile[i][tx] = w22[(size_t)(r0 + i) * 768 + c0 + tx];
            __syncthreads();
#pragma unroll
            for (int i = ty; i < 32; i += 8)
                w22T[(size_t)(c0 + i) * 768 + r0 + tx] = f2bf(tile[tx][i]);
        } else {
            int j = blk - 1920, bx = j % 24, by = j / 24;
            int c0 = bx << 5, r0 = by << 5, tx = tid & 31, ty = tid >> 5;
#pragma unroll
            for (int i = ty; i < 32; i += 8)
                tile[i][tx] = gw1[(size_t)(r0 + i) * 768 + c0 + tx];
            __syncthreads();
#pragma unroll
            for (int i = ty; i < 32; i += 8)
                gw1T[(size_t)(c0 + i) * 768 + r0 + tx] = f2bf(tile[tx][i]);
        }
    } else if (blk < 6496) {
        int e = blk - 2496;
        int t0 = trans[e], t1 = trans[N_EDGES + e];
        __shared__ int found;
        if (tid == 0) found = 0;
        __syncthreads();
        for (int j = tid; j < N_EDGES; j += 256)
            if (trans[j] == t1 && trans[N_EDGES + j] == t0) found = 1;  // benign race
        __syncthreads();
        float h = found ? 1.0f : 0.0f;
        short* rp = estack + (size_t)e * 128;
        if (tid < 20) {
            float x0 = data[t0 * 20 + tid];
            float x1 = data[t1 * 20 + tid];
            rp[tid]        = f2bf(x1);
            rp[20 + tid]   = f2bf(x0);
            rp[40 + tid]   = f2bf(h * x0);
            rp[60 + tid]   = f2bf(h * x1);
            rp[80 + tid]   = f2bf(x1 + h * x0);
            rp[100 + tid]  = f2bf(x0 + h * x1);
        } else if (tid < 28) {
            rp[120 + (tid - 20)] = 0;
        }
    } else if (blk < 8496) {
        int i = (blk - 6496) * 256 + tid;
        int r = i >> 7, c = i & 127;
        estack[(size_t)(4096) * 128 + i] = (c < 20) ? f2bf(data[r * 20 + c]) : (short)0;
    } else {
        int* partial = ibuf;
        int* excl    = ibuf + 256;
        int base = tid * 32;
        int cnt = 0;
        for (int i = 0; i < 32; ++i) {
            int idx = base + i;
            if (idx < T_ALL) cnt += (einx[idx] == 1);
        }
        partial[tid] = cnt;
        __syncthreads();
        if (tid == 0) {
            int s = 0;
            for (int i = 0; i < 256; ++i) { excl[i] = s; s += partial[i]; }
        }
        __syncthreads();
        int ce = excl[tid];
        int cn = base - ce;
        for (int i = 0; i < 32; ++i) {
            int idx = base + i;
            if (idx >= T_ALL) break;
            if (einx[idx] == 1) { src[idx] = ce; ce++; }
            else                { src[idx] = 4096 + cn; cn++; }
        }
    }
}

// One block per row: h1[r] = relu(sum_z partial_z[r] + bias); hw[r] = h1[r] @ w2
__global__ __launch_bounds__(192) void reduce_h1_hw(
    const short* __restrict__ p, const float* __restrict__ bias,
    const float* __restrict__ w2, float* __restrict__ h1, float* __restrict__ hw,
    int Z)
{
    int r = blockIdx.x, t = threadIdx.x;
    int c0 = t * 4;
    size_t base = (size_t)r * 768 + c0;
    float a[4];
#pragma unroll
    for (int j = 0; j < 4; ++j) a[j] = bias[c0 + j];
    for (int z = 0; z < Z; ++z) {
        s16x4 v = *reinterpret_cast<const s16x4*>(p + (size_t)z * 6144000 + base);
#pragma unroll
        for (int j = 0; j < 4; ++j) a[j] += bf2f(v[j]);
    }
    float d0 = 0.0f, d1 = 0.0f;
    float4 o;
#pragma unroll
    for (int j = 0; j < 4; ++j) {
        float v = fmaxf(a[j], 0.0f);
        ((float*)&o)[j] = v;
        d0 += v * w2[(c0 + j) * 2];
        d1 += v * w2[(c0 + j) * 2 + 1];
    }
    *reinterpret_cast<float4*>(h1 + base) = o;
#pragma unroll
    for (int off = 32; off > 0; off >>= 1) {
        d0 += __shfl_down(d0, off);
        d1 += __shfl_down(d1, off);
    }
    __shared__ float s0[3], s1[3];
    int wvv = t >> 6, ln = t & 63;
    if (ln == 0) { s0[wvv] = d0; s1[wvv] = d1; }
    __syncthreads();
    if (t == 0) {
        hw[r * 2]     = s0[0] + s0[1] + s0[2];
        hw[r * 2 + 1] = s1[0] + s1[1] + s1[2];
    }
}

// ---------------- small kernels -------------------------------------------

// fallback gather (src = direct F2s row)
__global__ void gather_x(const short* __restrict__ F2s, const int* __restrict__ src,
                         short* __restrict__ x)
{
    int i = blockIdx.x * 256 + threadIdx.x;
    int r = i / 96, c = i % 96;
    int s = src[r];
    reinterpret_cast<bf16x8*>(x)[i] =
        reinterpret_cast<const bf16x8*>(F2s + (size_t)s * HID)[c];
}

__global__ void h1w2_kernel(const float* __restrict__ h1, const float* __restrict__ w2,
                            float* __restrict__ hw)
{
    int wave = threadIdx.x >> 6, lane = threadIdx.x & 63;
    int row = blockIdx.x * 4 + wave;
    const float* hp = h1 + (size_t)row * HID;
    float a0 = 0.0f, a1 = 0.0f;
    for (int k = lane; k < HID; k += 64) {
        float h = hp[k];
        a0 += h * w2[k * 2];
        a1 += h * w2[k * 2 + 1];
    }
    for (int off = 32; off > 0; off >>= 1) {
        a0 += __shfl_down(a0, off);
        a1 += __shfl_down(a1, off);
    }
    if (lane == 0) { hw[row * 2] = a0; hw[row * 2 + 1] = a1; }
}

__global__ __launch_bounds__(256) void adj_hw_f32(const float* __restrict__ A,
    const float* __restrict__ hw, const float* __restrict__ b2, float* __restrict__ logits)
{
    int row = blockIdx.x;
    const float* ar = A + (size_t)row * T_ALL;
    float a0 = 0.0f, a1 = 0.0f;
    for (int k = threadIdx.x; k < T_ALL; k += 256) {
        float v = ar[k];
        a0 += v * hw[k * 2];
        a1 += v * hw[k * 2 + 1];
    }
    __shared__ float s0[256], s1[256];
    s0[threadIdx.x] = a0; s1[threadIdx.x] = a1;
    __syncthreads();
    for (int o = 128; o > 0; o >>= 1) {
        if (threadIdx.x < o) {
            s0[threadIdx.x] += s0[threadIdx.x + o];
            s1[threadIdx.x] += s1[threadIdx.x + o];
        }
        __syncthreads();
    }
    if (threadIdx.x == 0) {
        logits[row * 2]     = s0[0] + b2[0];
        logits[row * 2 + 1] = s1[0] + b2[1];
    }
}

__global__ __launch_bounds__(256) void loss_kernel(const float* __restrict__ logits,
    const int* __restrict__ label, const float* __restrict__ mask, float* __restrict__ outp)
{
    __shared__ float sc[256], sm[256];
    float ac = 0.0f, am = 0.0f;
    for (int i = threadIdx.x; i < T_ALL; i += 256) {
        float l0 = logits[i * 2], l1 = logits[i * 2 + 1];
        float mx = fmaxf(l0, l1);
        float lse = mx + logf(expf(l0 - mx) + expf(l1 - mx));
        float li = label[i] ? l1 : l0;
        ac += (lse - li) * mask[i];
        am += mask[i];
    }
    sc[threadIdx.x] = ac; sm[threadIdx.x] = am;
    __syncthreads();
    for (int o = 128; o > 0; o >>= 1) {
        if (threadIdx.x < o) {
            sc[threadIdx.x] += sc[threadIdx.x + o];
            sm[threadIdx.x] += sm[threadIdx.x + o];
        }
        __syncthreads();
    }
    if (threadIdx.x == 0) *outp = sc[0] / fmaxf(sm[0], 1.0f);
}

// ---------------- launch ---------------------------------------------------

extern "C" void kernel_launch(void* const* d_in, const int* in_sizes, int n_in,
                              void* d_out, int out_size, void* d_ws, size_t ws_size,
                              hipStream_t stream)
{
    (void)in_sizes; (void)n_in; (void)out_size;

    const float* data  = (const float*)d_in[0];
    const float* adj   = (const float*)d_in[2];
    const int*   trans = (const int*)d_in[3];
    const int*   einx  = (const int*)d_in[4];
    const int*   label = (const int*)d_in[5];
    const float* mask  = (const float*)d_in[6];
    const float* w1    = (const float*)d_in[7];
    const float* b1    = (const float*)d_in[8];
    const float* w2    = (const float*)d_in[9];
    const float* b2    = (const float*)d_in[10];
    const float* w21   = (const float*)d_in[11];
    const float* b21   = (const float*)d_in[12];
    const float* w22   = (const float*)d_in[13];
    const float* b22   = (const float*)d_in[14];
    const float* gw1   = (const float*)d_in[15];
    const float* gb1   = (const float*)d_in[16];
    const float* gw2   = (const float*)d_in[17];
    const float* gb2   = (const float*)d_in[18];

    char* W = (char*)d_ws;
    // transient region (dead before gemm_ring writes parts)
    short* w1T    = (short*)(W + 0);
    short* w2T    = (short*)(W + 196608);
    short* w21T   = (short*)(W + 1376256);
    short* w22T   = (short*)(W + 1572864);
    short* gw1T   = (short*)(W + 2752512);
    short* estack = (short*)(W + 3932160);
    short* C1s    = (short*)(W + 6029312);
    short* F2s    = (short*)(W + 18612224);
    short* xbuf   = (short*)(W + 31195136);
    int*   src    = (int*)(W + 43499136);

    const bool ok = (ws_size >= (size_t)110656000);

    float* out    = (float*)d_out;
    float* logits = out;
    float* lossp  = out + 16000;
    float* h1     = out + 16001;

    if (ok) {
        short* parts = (short*)(W + 0);              // 8 * 8000*768 bf16 (aliases transient)
        short* xwT   = (short*)(W + 98304000);       // [768][8000]
        float* hwbuf = (float*)(W + 110592000);      // ends 110,656,000

        // 1) prep (no cvt)
        prep_all<<<8497, 256, 0, stream>>>(data, trans, w1, w2, w21, w22, gw1, einx,
                                           w1T, w2T, w21T, w22T, gw1T, estack, src);
        // 2) merged MLPs
        gemm_sel<1><<<dim3(6, 64), 256, 0, stream>>>(estack, w1T, w21T, b1, b21, C1s, 128);
        gemm_sel<0><<<dim3(6, 64), 256, 0, stream>>>(C1s, w2T, w22T, b2, b22, F2s, 768);
        // 3) xwT = gw1^T @ x^T with fused gather
        gemm_bf<0, 0, 1, 0, 1><<<dim3(63, 6), 256, 0, stream>>>(
            gw1T, F2s, nullptr, xwT, 768, 8000, 768, 768, 768, 8000, src);
        // 4) big GEMM: f32-A reg-staged ring, split-K Z=8, fused reduce+h1w2
        gemm_ring<<<dim3(3, 32, 8), 512, 0, stream>>>(adj, xwT, parts, 8000, 8000, 8000, 8000);
        reduce_h1_hw<<<8000, 192, 0, stream>>>(parts, gb1, gw2, h1, hwbuf, 8);
        // 5) logits + loss (f32 adj)
        adj_hw_f32<<<8000, 256, 0, stream>>>(adj, hwbuf, gb2, logits);
        loss_kernel<<<1, 256, 0, stream>>>(logits, label, mask, lossp);
        return;
    }

    // ---------- small fallback (ws < 110.7 MB): f32 A reg-staged 128² -------
    short* xwT   = (short*)(W + 48425856);
    float* hwbuf = (float*)(W + 60713856);

    prep_all<<<8497, 256, 0, stream>>>(data, trans, w1, w2, w21, w22, gw1, einx,
                                       w1T, w2T, w21T, w22T, gw1T, estack, src);
    gemm_sel<1><<<dim3(6, 64), 256, 0, stream>>>(estack, w1T, w21T, b1, b21, C1s, 128);
    gemm_sel<0><<<dim3(6, 64), 256, 0, stream>>>(C1s, w2T, w22T, b2, b22, F2s, 768);
    gather_x<<<3000, 256, 0, stream>>>(F2s, src, xbuf);
    gemm_bf<0, 0, 1, 0, 0><<<dim3(63, 6), 256, 0, stream>>>(
        gw1T, xbuf, nullptr, xwT, 768, 8000, 768, 768, 768, 8000, nullptr);
    gemm_bf<1, 1, 0, 1, 0><<<dim3(6, 63), 256, 0, stream>>>(
        adj, xwT, gb1, h1, 8000, 768, 8000, 8000, 8000, 768, nullptr);
    h1w2_kernel<<<2000, 256, 0, stream>>>(h1, gw2, hwbuf);
    adj_hw_f32<<<8000, 256, 0, stream>>>(adj, hwbuf, gb2, logits);
    loss_kernel<<<1, 256, 0, stream>>>(logits, label, mask, lossp);
}

// Round 16
// 305.650 us; speedup vs baseline: 1.4740x; 1.4740x over previous
//
#include <hip/hip_runtime.h>
#include <hip/hip_bf16.h>

#define N_NODES 4000
#define N_EDGES 4000
#define T_ALL   8000
#define HID     768

typedef __attribute__((ext_vector_type(8))) short bf16x8;
typedef __attribute__((ext_vector_type(4))) short s16x4;
typedef __attribute__((ext_vector_type(4))) float f32x4;

__device__ __forceinline__ short f2bf(float f) {
    union { float f; unsigned u; } a; a.f = f;
    unsigned u = a.u;
    unsigned r = (u + 0x7fffu + ((u >> 16) & 1u)) >> 16;   // RNE
    return (short)(r & 0xffffu);
}
__device__ __forceinline__ float bf2f(short s) {
    union { unsigned u; float f; } a;
    a.u = ((unsigned)(unsigned short)s) << 16;
    return a.f;
}
__device__ __forceinline__ void gload_lds16(const void* g, void* l) {
    __builtin_amdgcn_global_load_lds(
        (const __attribute__((address_space(1))) void*)g,
        (__attribute__((address_space(3))) void*)l, 16, 0, 0);
}

// cvt job: one block converts 2048 floats -> bf16
__device__ __forceinline__ void cvt_job(const float* __restrict__ src,
                                        short* __restrict__ dst, int chunk)
{
    size_t i = (size_t)chunk * 2048 + threadIdx.x * 8;
    float4 v0 = *reinterpret_cast<const float4*>(src + i);
    float4 v1 = *reinterpret_cast<const float4*>(src + i + 4);
    union { bf16x8 v; short s[8]; } u;
    u.s[0] = f2bf(v0.x); u.s[1] = f2bf(v0.y); u.s[2] = f2bf(v0.z); u.s[3] = f2bf(v0.w);
    u.s[4] = f2bf(v1.x); u.s[5] = f2bf(v1.y); u.s[6] = f2bf(v1.z); u.s[7] = f2bf(v1.w);
    *reinterpret_cast<bf16x8*>(dst + i) = u.v;
}

// ===== big GEMM: 256x256, K32-tile ring-4, register-lookahead (r10 best) ====
__global__ __launch_bounds__(512, 2) void gemm_ring(
    const short* __restrict__ A, const short* __restrict__ BT,
    short* __restrict__ parts, int M, int K, int lda, int ldbt)
{
    __shared__ __align__(16) short As[4][256 * 32];
    __shared__ __align__(16) short Bs[4][256 * 32];
    const int t    = threadIdx.x;
    const int lane = t & 63;
    const int wv   = t >> 6;
    const int wm   = wv >> 2;
    const int wn   = wv & 3;
    const int lrow = lane & 15;
    const int kgrp = lane >> 4;

    const int nwg  = gridDim.x * gridDim.y * gridDim.z;
    int flat = blockIdx.x + gridDim.x * (blockIdx.y + gridDim.y * blockIdx.z);
    int w    = (flat & 7) * (nwg >> 3) + (flat >> 3);
    const int bx = w % 3;
    int rest = w / 3;
    const int by = rest & 31;
    const int bz = rest >> 5;
    const int bm0 = by << 8;
    const int bn0 = bx << 8;

    const int TC = K >> 5;
    const int Z  = gridDim.z;
    const int q  = TC / Z, r = TC % Z;
    const int nt   = q + (bz < r ? 1 : 0);
    const int kbeg = ((bz < r) ? bz * (q + 1) : r * (q + 1) + (bz - r) * q) << 5;

    auto stageA = [&](int tt) {
        const int k0 = kbeg + (tt << 5);
        short* dst = &As[tt & 3][0];
#pragma unroll
        for (int i = 0; i < 2; ++i) {
            int f = t + (i << 9);
            int row = f >> 2, sl = f & 3;
            int ga = bm0 + row; ga = ga < M ? ga : M - 1;
            gload_lds16(A + (size_t)ga * lda + k0 + ((sl ^ ((row >> 1) & 3)) << 3),
                        dst + f * 8);
        }
    };
    auto stageB = [&](int tt) {
        const int k0 = kbeg + (tt << 5);
        short* dst = &Bs[tt & 3][0];
#pragma unroll
        for (int i = 0; i < 2; ++i) {
            int f = t + (i << 9);
            int row = f >> 2, sl = f & 3;
            gload_lds16(BT + (size_t)(bn0 + row) * ldbt + k0 + ((sl ^ ((row >> 1) & 3)) << 3),
                        dst + f * 8);
        }
    };

    f32x4 acc[8][4];
#pragma unroll
    for (int m = 0; m < 8; ++m)
#pragma unroll
        for (int n = 0; n < 4; ++n) acc[m][n] = (f32x4)(0.0f);

    stageA(0); stageB(0);
    stageA(1); stageB(1);
    stageA(2); stageB(2);
    asm volatile("s_waitcnt vmcnt(4)" ::: "memory");
    __builtin_amdgcn_s_barrier();

    bf16x8 r0A0[4], r0A1[4], r0B[4];
    bf16x8 r1A0[4], r1A1[4], r1B[4];

    {
        const short* Ac = &As[0][0];
        const short* Bc = &Bs[0][0];
#pragma unroll
        for (int m = 0; m < 4; ++m) {
            int rr = (wm << 7) + (m << 4) + lrow;
            r0A0[m] = *reinterpret_cast<const bf16x8*>(
                &Ac[(rr << 5) + ((kgrp ^ ((rr >> 1) & 3)) << 3)]);
        }
#pragma unroll
        for (int n = 0; n < 4; ++n) {
            int rr = (wn << 6) + (n << 4) + lrow;
            r0B[n] = *reinterpret_cast<const bf16x8*>(
                &Bc[(rr << 5) + ((kgrp ^ ((rr >> 1) & 3)) << 3)]);
        }
#pragma unroll
        for (int m = 0; m < 4; ++m) {
            int rr = (wm << 7) + 64 + (m << 4) + lrow;
            r0A1[m] = *reinterpret_cast<const bf16x8*>(
                &Ac[(rr << 5) + ((kgrp ^ ((rr >> 1) & 3)) << 3)]);
        }
    }

#define TILE_STEP(TT, cA0, cA1, cB, nA0, nA1, nB)                              \
    {                                                                          \
        const int _tt = (TT);                                                  \
        if (_tt + 1 < nt) {                                                    \
            const short* An = &As[(_tt + 1) & 3][0];                           \
            const short* Bn = &Bs[(_tt + 1) & 3][0];                           \
            _Pragma("unroll")                                                  \
            for (int m = 0; m < 4; ++m) {                                      \
                int rr = (wm << 7) + (m << 4) + lrow;                          \
                nA0[m] = *reinterpret_cast<const bf16x8*>(                     \
                    &An[(rr << 5) + ((kgrp ^ ((rr >> 1) & 3)) << 3)]);         \
            }                                                                  \
            _Pragma("unroll")                                                  \
            for (int n = 0; n < 4; ++n) {                                      \
                int rr = (wn << 6) + (n << 4) + lrow;                          \
                nB[n] = *reinterpret_cast<const bf16x8*>(                      \
                    &Bn[(rr << 5) + ((kgrp ^ ((rr >> 1) & 3)) << 3)]);         \
            }                                                                  \
            _Pragma("unroll")                                                  \
            for (int m = 0; m < 4; ++m) {                                      \
                int rr = (wm << 7) + 64 + (m << 4) + lrow;                     \
                nA1[m] = *reinterpret_cast<const bf16x8*>(                     \
                    &An[(rr << 5) + ((kgrp ^ ((rr >> 1) & 3)) << 3)]);         \
            }                                                                  \
        }                                                                      \
        if (_tt + 3 < nt) { stageA(_tt + 3); stageB(_tt + 3); }                \
        __builtin_amdgcn_sched_barrier(0);                                     \
        __builtin_amdgcn_s_setprio(1);                                         \
        _Pragma("unroll")                                                      \
        for (int m = 0; m < 4; ++m)                                            \
            _Pragma("unroll")                                                  \
            for (int n = 0; n < 4; ++n)                                        \
                acc[m][n] = __builtin_amdgcn_mfma_f32_16x16x32_bf16(           \
                    cA0[m], cB[n], acc[m][n], 0, 0, 0);                        \
        _Pragma("unroll")                                                      \
        for (int m = 0; m < 4; ++m)                                            \
            _Pragma("unroll")                                                  \
            for (int n = 0; n < 4; ++n)                                        \
                acc[4 + m][n] = __builtin_amdgcn_mfma_f32_16x16x32_bf16(       \
                    cA1[m], cB[n], acc[4 + m][n], 0, 0, 0);                    \
        __builtin_amdgcn_s_setprio(0);                                         \
        if (_tt <= nt - 4) asm volatile("s_waitcnt vmcnt(4)" ::: "memory");    \
        else               asm volatile("s_waitcnt vmcnt(0)" ::: "memory");    \
        __builtin_amdgcn_s_barrier();                                          \
    }

    int tt = 0;
    for (; tt + 1 < nt; tt += 2) {
        TILE_STEP(tt,     r0A0, r0A1, r0B, r1A0, r1A1, r1B);
        TILE_STEP(tt + 1, r1A0, r1A1, r1B, r0A0, r0A1, r0B);
    }
    if (tt < nt) TILE_STEP(tt, r0A0, r0A1, r0B, r1A0, r1A1, r1B);
#undef TILE_STEP

    short* Cp = parts + (size_t)bz * 6144000;
#pragma unroll
    for (int m = 0; m < 8; ++m) {
        int r0 = bm0 + (wm << 7) + (m << 4) + (kgrp << 2);
#pragma unroll
        for (int n = 0; n < 4; ++n) {
            int col = bn0 + (wn << 6) + (n << 4) + lrow;
#pragma unroll
            for (int j = 0; j < 4; ++j) {
                int rr = r0 + j;
                if (rr < M) Cp[(size_t)rr * 768 + col] = f2bf(acc[m][n][j]);
            }
        }
    }
}

// ---------------- GEMM: C[M,N] = A[M,K] * B  (B given as BT[N,K], bf16) ----
// GAT=1: B rows indirected via srcmap (fused gather).
template<int BIAS, int RELU, int OUTBF, int AF32, int GAT>
__global__ __launch_bounds__(256) void gemm_bf(
    const void* __restrict__ Av, const short* __restrict__ BT,
    const float* __restrict__ bias, void* __restrict__ Cv,
    int M, int N, int K, int lda, int ldbt, int ldc,
    const int* __restrict__ srcmap)
{
    __shared__ __align__(16) short As[2][128 * 64];
    __shared__ __align__(16) short Bs[2][128 * 64];
    const int t    = threadIdx.x;
    const int lane = t & 63;
    const int wave = t >> 6;
    const int wr   = (wave >> 1) << 6;
    const int wc   = (wave & 1) << 6;
    const int lrow = lane & 15;
    const int kgrp = lane >> 4;
    const int bm0  = blockIdx.y << 7;
    const int bn0  = blockIdx.x << 7;
    const short* Ab = (const short*)Av;
    const float* Af = (const float*)Av;

    const int nk = K >> 6;

    auto stage = [&](int kt, int buf) {
        const int k0 = kt << 6;
#pragma unroll
        for (int i = 0; i < 4; ++i) {
            int f = t + (i << 8);
            int row = f >> 3, slot = f & 7;
            int gb = bn0 + row; gb = (gb < N) ? gb : (N - 1);
            int sr = GAT ? srcmap[gb] : gb;
            gload_lds16(BT + (size_t)sr * ldbt + k0 + ((slot ^ (row & 7)) << 3),
                        &Bs[buf][((i << 8) + (wave << 6)) * 8]);
        }
        if constexpr (!AF32) {
#pragma unroll
            for (int i = 0; i < 4; ++i) {
                int f = t + (i << 8);
                int row = f >> 3, slot = f & 7;
                int ga = bm0 + row; ga = (ga < M) ? ga : (M - 1);
                gload_lds16(Ab + (size_t)ga * lda + k0 + ((slot ^ (row & 7)) << 3),
                            &As[buf][((i << 8) + (wave << 6)) * 8]);
            }
        } else {
#pragma unroll
            for (int i = 0; i < 4; ++i) {
                int f = t + (i << 8);
                int row = f >> 3, c8 = f & 7;
                int ga = bm0 + row; ga = (ga < M) ? ga : (M - 1);
                const float* ap = Af + (size_t)ga * lda + k0 + (c8 << 3);
                float4 v0 = *reinterpret_cast<const float4*>(ap);
                float4 v1 = *reinterpret_cast<const float4*>(ap + 4);
                union { bf16x8 v; short s[8]; } u;
                u.s[0] = f2bf(v0.x); u.s[1] = f2bf(v0.y); u.s[2] = f2bf(v0.z); u.s[3] = f2bf(v0.w);
                u.s[4] = f2bf(v1.x); u.s[5] = f2bf(v1.y); u.s[6] = f2bf(v1.z); u.s[7] = f2bf(v1.w);
                *reinterpret_cast<bf16x8*>(&As[buf][row * 64 + ((c8 ^ (row & 7)) << 3)]) = u.v;
            }
        }
    };

    f32x4 acc[4][4];
#pragma unroll
    for (int m = 0; m < 4; ++m)
#pragma unroll
        for (int n = 0; n < 4; ++n) acc[m][n] = (f32x4)(0.0f);

    auto compute = [&](int buf) {
#pragma unroll
        for (int kk = 0; kk < 2; ++kk) {
            bf16x8 af[4], bfv[4];
#pragma unroll
            for (int m = 0; m < 4; ++m) {
                int rr = wr + m * 16 + lrow;
                af[m] = *reinterpret_cast<const bf16x8*>(
                    &As[buf][rr * 64 + (((kk * 4 + kgrp) ^ (rr & 7)) << 3)]);
            }
#pragma unroll
            for (int n = 0; n < 4; ++n) {
                int rr = wc + n * 16 + lrow;
                bfv[n] = *reinterpret_cast<const bf16x8*>(
                    &Bs[buf][rr * 64 + (((kk * 4 + kgrp) ^ (rr & 7)) << 3)]);
            }
#pragma unroll
            for (int m = 0; m < 4; ++m)
#pragma unroll
                for (int n = 0; n < 4; ++n)
                    acc[m][n] = __builtin_amdgcn_mfma_f32_16x16x32_bf16(
                        af[m], bfv[n], acc[m][n], 0, 0, 0);
        }
    };

    if constexpr (!AF32) {
        stage(0, 0);
        if (nk > 1) stage(1, 1);
        for (int kt = 0; kt < nk - 1; ++kt) {
            asm volatile("s_waitcnt vmcnt(8)" ::: "memory");
            __builtin_amdgcn_s_barrier();
            compute(kt & 1);
            __builtin_amdgcn_s_barrier();
            if (kt + 2 < nk) stage(kt + 2, kt & 1);
        }
        asm volatile("s_waitcnt vmcnt(0)" ::: "memory");
        __builtin_amdgcn_s_barrier();
        compute((nk - 1) & 1);
    } else {
        stage(0, 0);
        __syncthreads();
        int cur = 0;
        for (int kt = 0; kt < nk; ++kt) {
            if (kt + 1 < nk) stage(kt + 1, cur ^ 1);
            compute(cur);
            __syncthreads();
            cur ^= 1;
        }
    }

    short* Cb = (short*)Cv;
    float* Cf = (float*)Cv;
#pragma unroll
    for (int m = 0; m < 4; ++m) {
        int rbase = bm0 + wr + m * 16 + kgrp * 4;
#pragma unroll
        for (int n = 0; n < 4; ++n) {
            int col = bn0 + wc + n * 16 + lrow;
            if (col >= N) continue;
            float bv = BIAS ? bias[col] : 0.0f;
#pragma unroll
            for (int j = 0; j < 4; ++j) {
                int rr = rbase + j;
                if (rr < M) {
                    float v = acc[m][n][j] + bv;
                    if (RELU) v = fmaxf(v, 0.0f);
                    if (OUTBF) Cb[(size_t)rr * ldc + col] = f2bf(v);
                    else       Cf[(size_t)rr * ldc + col] = v;
                }
            }
        }
    }
}

// ---- stacked-M MLP GEMM: M=8192 (edge rows 0.., node rows 4096..), N=768 ---
template<int RELU>
__global__ __launch_bounds__(256) void gemm_sel(
    const short* __restrict__ A,
    const short* __restrict__ BT1, const short* __restrict__ BT2,
    const float* __restrict__ bias1, const float* __restrict__ bias2,
    short* __restrict__ C, int K)
{
    __shared__ __align__(16) short As[2][128 * 64];
    __shared__ __align__(16) short Bs[2][128 * 64];
    const int t    = threadIdx.x;
    const int lane = t & 63;
    const int wave = t >> 6;
    const int wr   = (wave >> 1) << 6;
    const int wc   = (wave & 1) << 6;
    const int lrow = lane & 15;
    const int kgrp = lane >> 4;
    const int bm0  = blockIdx.y << 7;
    const int bn0  = blockIdx.x << 7;
    const short* BT   = (bm0 < 4096) ? BT1 : BT2;
    const float* bias = (bm0 < 4096) ? bias1 : bias2;
    const int nk = K >> 6;

    auto stage = [&](int kt, int buf) {
        const int k0 = kt << 6;
#pragma unroll
        for (int i = 0; i < 4; ++i) {
            int f = t + (i << 8);
            int row = f >> 3, slot = f & 7;
            gload_lds16(BT + (size_t)(bn0 + row) * K + k0 + ((slot ^ (row & 7)) << 3),
                        &Bs[buf][((i << 8) + (wave << 6)) * 8]);
        }
#pragma unroll
        for (int i = 0; i < 4; ++i) {
            int f = t + (i << 8);
            int row = f >> 3, slot = f & 7;
            gload_lds16(A + (size_t)(bm0 + row) * K + k0 + ((slot ^ (row & 7)) << 3),
                        &As[buf][((i << 8) + (wave << 6)) * 8]);
        }
    };

    f32x4 acc[4][4];
#pragma unroll
    for (int m = 0; m < 4; ++m)
#pragma unroll
        for (int n = 0; n < 4; ++n) acc[m][n] = (f32x4)(0.0f);

    auto compute = [&](int buf) {
#pragma unroll
        for (int kk = 0; kk < 2; ++kk) {
            bf16x8 af[4], bfv[4];
#pragma unroll
            for (int m = 0; m < 4; ++m) {
                int rr = wr + m * 16 + lrow;
                af[m] = *reinterpret_cast<const bf16x8*>(
                    &As[buf][rr * 64 + (((kk * 4 + kgrp) ^ (rr & 7)) << 3)]);
            }
#pragma unroll
            for (int n = 0; n < 4; ++n) {
                int rr = wc + n * 16 + lrow;
                bfv[n] = *reinterpret_cast<const bf16x8*>(
                    &Bs[buf][rr * 64 + (((kk * 4 + kgrp) ^ (rr & 7)) << 3)]);
            }
#pragma unroll
            for (int m = 0; m < 4; ++m)
#pragma unroll
                for (int n = 0; n < 4; ++n)
                    acc[m][n] = __builtin_amdgcn_mfma_f32_16x16x32_bf16(
                        af[m], bfv[n], acc[m][n], 0, 0, 0);
        }
    };

    stage(0, 0);
    if (nk > 1) stage(1, 1);
    for (int kt = 0; kt < nk - 1; ++kt) {
        asm volatile("s_waitcnt vmcnt(8)" ::: "memory");
        __builtin_amdgcn_s_barrier();
        compute(kt & 1);
        __builtin_amdgcn_s_barrier();
        if (kt + 2 < nk) stage(kt + 2, kt & 1);
    }
    asm volatile("s_waitcnt vmcnt(0)" ::: "memory");
    __builtin_amdgcn_s_barrier();
    compute((nk - 1) & 1);

#pragma unroll
    for (int m = 0; m < 4; ++m) {
        int rbase = bm0 + wr + m * 16 + kgrp * 4;
#pragma unroll
        for (int n = 0; n < 4; ++n) {
            int col = bn0 + wc + n * 16 + lrow;
            float bv = bias[col];
#pragma unroll
            for (int j = 0; j < 4; ++j) {
                float v = acc[m][n][j] + bv;
                if (RELU) v = fmaxf(v, 0.0f);
                C[(size_t)(rbase + j) * 768 + col] = f2bf(v);
            }
        }
    }
}

// ====== prep_all: transposes + edge rows + node pad + build_src + cvt tail ==
// build_src emits the F2s ROW INDEX directly: edge -> row e, node -> 4096+n
__global__ __launch_bounds__(256) void prep_all(
    const float* __restrict__ data, const int* __restrict__ trans,
    const float* __restrict__ w1, const float* __restrict__ w2,
    const float* __restrict__ w21, const float* __restrict__ w22,
    const float* __restrict__ gw1, const int* __restrict__ einx,
    short* __restrict__ w1T, short* __restrict__ w2T,
    short* __restrict__ w21T, short* __restrict__ w22T,
    short* __restrict__ gw1T, short* __restrict__ estack,
    int* __restrict__ src,
    const float* __restrict__ cvsrc, short* __restrict__ cvdst,
    int cvoff, int cvcnt)
{
    __shared__ float tile[32][33];
    __shared__ int ibuf[512];
    const int blk = blockIdx.x, tid = threadIdx.x;

    if (blk >= 8497) {
        int jid = blk - 8497;
        if (jid < cvcnt) cvt_job(cvsrc, cvdst, jid + cvoff);
        return;
    }

    if (blk < 2496) {
        if (blk < 384) {
            int i = blk * 256 + tid, n = i >> 7, k = i & 127;
            w1T[i] = (k < 120) ? f2bf(w1[k * 768 + n]) : (short)0;
        } else if (blk < 1344) {
            if (blk < 960) {
                int j = blk - 384, bx = j % 24, by = j / 24;
                int c0 = bx << 5, r0 = by << 5, tx = tid & 31, ty = tid >> 5;
#pragma unroll
                for (int i = ty; i < 32; i += 8)
                    tile[i][tx] = w2[(size_t)(r0 + i) * 768 + c0 + tx];
                __syncthreads();
#pragma unroll
                for (int i = ty; i < 32; i += 8)
                    w2T[(size_t)(c0 + i) * 768 + r0 + tx] = f2bf(tile[tx][i]);
            } else {
                int i = (blk - 960) * 256 + tid, n = i >> 7, k = i & 127;
                w21T[i] = (k < 20) ? f2bf(w21[k * 768 + n]) : (short)0;
            }
        } else if (blk < 1920) {
            int j = blk - 1344, bx = j % 24, by = j / 24;
            int c0 = bx << 5, r0 = by << 5, tx = tid & 31, ty = tid >> 5;
#pragma unroll
            for (int i = ty; i < 32; i += 8)
                tile[i][tx] = w22[(size_t)(r0 + i) * 768 + c0 + tx];
            __syncthreads();
#pragma unroll
            for (int i = ty; i < 32; i += 8)
                w22T[(size_t)(c0 + i) * 768 + r0 + tx] = f2bf(tile[tx][i]);
        } else {
            int j = blk - 1920, bx = j % 24, by = j / 24;
            int c0 = bx << 5, r0 = by << 5, tx = tid & 31, ty = tid >> 5;
#pragma unroll
            for (int i = ty; i < 32; i += 8)
                tile[i][tx] = gw1[(size_t)(r0 + i) * 768 + c0 + tx];
            __syncthreads();
#pragma unroll
            for (int i = ty; i < 32; i += 8)
                gw1T[(size_t)(c0 + i) * 768 + r0 + tx] = f2bf(tile[tx][i]);
        }
    } else if (blk < 6496) {
        int e = blk - 2496;
        int t0 = trans[e], t1 = trans[N_EDGES + e];
        __shared__ int found;
        if (tid == 0) found = 0;
        __syncthreads();
        for (int j = tid; j < N_EDGES; j += 256)
            if (trans[j] == t1 && trans[N_EDGES + j] == t0) found = 1;  // benign race
        __syncthreads();
        float h = found ? 1.0f : 0.0f;
        short* rp = estack + (size_t)e * 128;
        if (tid < 20) {
            float x0 = data[t0 * 20 + tid];
            float x1 = data[t1 * 20 + tid];
            rp[tid]        = f2bf(x1);
            rp[20 + tid]   = f2bf(x0);
            rp[40 + tid]   = f2bf(h * x0);
            rp[60 + tid]   = f2bf(h * x1);
            rp[80 + tid]   = f2bf(x1 + h * x0);
            rp[100 + tid]  = f2bf(x0 + h * x1);
        } else if (tid < 28) {
            rp[120 + (tid - 20)] = 0;
        }
    } else if (blk < 8496) {
        int i = (blk - 6496) * 256 + tid;
        int r = i >> 7, c = i & 127;
        estack[(size_t)(4096) * 128 + i] = (c < 20) ? f2bf(data[r * 20 + c]) : (short)0;
    } else {
        int* partial = ibuf;
        int* excl    = ibuf + 256;
        int base = tid * 32;
        int cnt = 0;
        for (int i = 0; i < 32; ++i) {
            int idx = base + i;
            if (idx < T_ALL) cnt += (einx[idx] == 1);
        }
        partial[tid] = cnt;
        __syncthreads();
        if (tid == 0) {
            int s = 0;
            for (int i = 0; i < 256; ++i) { excl[i] = s; s += partial[i]; }
        }
        __syncthreads();
        int ce = excl[tid];
        int cn = base - ce;
        for (int i = 0; i < 32; ++i) {
            int idx = base + i;
            if (idx >= T_ALL) break;
            if (einx[idx] == 1) { src[idx] = ce; ce++; }           // F2s edge row
            else                { src[idx] = 4096 + cn; cn++; }    // F2s node row
        }
    }
}

// One block per row: h1[r] = relu(sum_z partial_z[r] + bias); hw[r] = h1[r] @ w2
__global__ __launch_bounds__(192) void reduce_h1_hw(
    const short* __restrict__ p, const float* __restrict__ bias,
    const float* __restrict__ w2, float* __restrict__ h1, float* __restrict__ hw,
    int Z)
{
    int r = blockIdx.x, t = threadIdx.x;
    int c0 = t * 4;
    size_t base = (size_t)r * 768 + c0;
    float a[4];
#pragma unroll
    for (int j = 0; j < 4; ++j) a[j] = bias[c0 + j];
    for (int z = 0; z < Z; ++z) {
        s16x4 v = *reinterpret_cast<const s16x4*>(p + (size_t)z * 6144000 + base);
#pragma unroll
        for (int j = 0; j < 4; ++j) a[j] += bf2f(v[j]);
    }
    float d0 = 0.0f, d1 = 0.0f;
    float4 o;
#pragma unroll
    for (int j = 0; j < 4; ++j) {
        float v = fmaxf(a[j], 0.0f);
        ((float*)&o)[j] = v;
        d0 += v * w2[(c0 + j) * 2];
        d1 += v * w2[(c0 + j) * 2 + 1];
    }
    *reinterpret_cast<float4*>(h1 + base) = o;
#pragma unroll
    for (int off = 32; off > 0; off >>= 1) {
        d0 += __shfl_down(d0, off);
        d1 += __shfl_down(d1, off);
    }
    __shared__ float s0[3], s1[3];
    int wvv = t >> 6, ln = t & 63;
    if (ln == 0) { s0[wvv] = d0; s1[wvv] = d1; }
    __syncthreads();
    if (t == 0) {
        hw[r * 2]     = s0[0] + s0[1] + s0[2];
        hw[r * 2 + 1] = s1[0] + s1[1] + s1[2];
    }
}

// ---------------- small kernels -------------------------------------------

__global__ void cvt_bf16(const float* __restrict__ in, short* __restrict__ out, int n8)
{
    int i = blockIdx.x * 256 + threadIdx.x;
    if (i >= n8) return;
    float4 v0 = *reinterpret_cast<const float4*>(in + (size_t)i * 8);
    float4 v1 = *reinterpret_cast<const float4*>(in + (size_t)i * 8 + 4);
    union { bf16x8 v; short s[8]; } u;
    u.s[0] = f2bf(v0.x); u.s[1] = f2bf(v0.y); u.s[2] = f2bf(v0.z); u.s[3] = f2bf(v0.w);
    u.s[4] = f2bf(v1.x); u.s[5] = f2bf(v1.y); u.s[6] = f2bf(v1.z); u.s[7] = f2bf(v1.w);
    *reinterpret_cast<bf16x8*>(out + (size_t)i * 8) = u.v;
}

// fallback gather (new src semantics: direct F2s row)
__global__ void gather_x(const short* __restrict__ F2s, const int* __restrict__ src,
                         short* __restrict__ x)
{
    int i = blockIdx.x * 256 + threadIdx.x;
    int r = i / 96, c = i % 96;
    int s = src[r];
    reinterpret_cast<bf16x8*>(x)[i] =
        reinterpret_cast<const bf16x8*>(F2s + (size_t)s * HID)[c];
}

__global__ void h1w2_kernel(const float* __restrict__ h1, const float* __restrict__ w2,
                            float* __restrict__ hw)
{
    int wave = threadIdx.x >> 6, lane = threadIdx.x & 63;
    int row = blockIdx.x * 4 + wave;
    const float* hp = h1 + (size_t)row * HID;
    float a0 = 0.0f, a1 = 0.0f;
    for (int k = lane; k < HID; k += 64) {
        float h = hp[k];
        a0 += h * w2[k * 2];
        a1 += h * w2[k * 2 + 1];
    }
    for (int off = 32; off > 0; off >>= 1) {
        a0 += __shfl_down(a0, off);
        a1 += __shfl_down(a1, off);
    }
    if (lane == 0) { hw[row * 2] = a0; hw[row * 2 + 1] = a1; }
}

__global__ __launch_bounds__(256) void adj_hw_bf(const short* __restrict__ A,
    const float* __restrict__ hw, const float* __restrict__ b2, float* __restrict__ logits)
{
    int row = blockIdx.x;
    const short* ar = A + (size_t)row * T_ALL;
    float a0 = 0.0f, a1 = 0.0f;
    for (int c = threadIdx.x; c < 1000; c += 256) {
        bf16x8 v = *reinterpret_cast<const bf16x8*>(ar + c * 8);
#pragma unroll
        for (int j = 0; j < 8; ++j) {
            float av = bf2f(v[j]);
            int k = c * 8 + j;
            a0 += av * hw[k * 2];
            a1 += av * hw[k * 2 + 1];
        }
    }
    __shared__ float s0[256], s1[256];
    s0[threadIdx.x] = a0; s1[threadIdx.x] = a1;
    __syncthreads();
    for (int o = 128; o > 0; o >>= 1) {
        if (threadIdx.x < o) {
            s0[threadIdx.x] += s0[threadIdx.x + o];
            s1[threadIdx.x] += s1[threadIdx.x + o];
        }
        __syncthreads();
    }
    if (threadIdx.x == 0) {
        logits[row * 2]     = s0[0] + b2[0];
        logits[row * 2 + 1] = s1[0] + b2[1];
    }
}

__global__ __launch_bounds__(256) void adj_hw_f32(const float* __restrict__ A,
    const float* __restrict__ hw, const float* __restrict__ b2, float* __restrict__ logits)
{
    int row = blockIdx.x;
    const float* ar = A + (size_t)row * T_ALL;
    float a0 = 0.0f, a1 = 0.0f;
    for (int k = threadIdx.x; k < T_ALL; k += 256) {
        float v = ar[k];
        a0 += v * hw[k * 2];
        a1 += v * hw[k * 2 + 1];
    }
    __shared__ float s0[256], s1[256];
    s0[threadIdx.x] = a0; s1[threadIdx.x] = a1;
    __syncthreads();
    for (int o = 128; o > 0; o >>= 1) {
        if (threadIdx.x < o) {
            s0[threadIdx.x] += s0[threadIdx.x + o];
            s1[threadIdx.x] += s1[threadIdx.x + o];
        }
        __syncthreads();
    }
    if (threadIdx.x == 0) {
        logits[row * 2]     = s0[0] + b2[0];
        logits[row * 2 + 1] = s1[0] + b2[1];
    }
}

__global__ __launch_bounds__(256) void loss_kernel(const float* __restrict__ logits,
    const int* __restrict__ label, const float* __restrict__ mask, float* __restrict__ outp)
{
    __shared__ float sc[256], sm[256];
    float ac = 0.0f, am = 0.0f;
    for (int i = threadIdx.x; i < T_ALL; i += 256) {
        float l0 = logits[i * 2], l1 = logits[i * 2 + 1];
        float mx = fmaxf(l0, l1);
        float lse = mx + logf(expf(l0 - mx) + expf(l1 - mx));
        float li = label[i] ? l1 : l0;
        ac += (lse - li) * mask[i];
        am += mask[i];
    }
    sc[threadIdx.x] = ac; sm[threadIdx.x] = am;
    __syncthreads();
    for (int o = 128; o > 0; o >>= 1) {
        if (threadIdx.x < o) {
            sc[threadIdx.x] += sc[threadIdx.x + o];
            sm[threadIdx.x] += sm[threadIdx.x + o];
        }
        __syncthreads();
    }
    if (threadIdx.x == 0) *outp = sc[0] / fmaxf(sm[0], 1.0f);
}

// ---------------- launch ---------------------------------------------------

extern "C" void kernel_launch(void* const* d_in, const int* in_sizes, int n_in,
                              void* d_out, int out_size, void* d_ws, size_t ws_size,
                              hipStream_t stream)
{
    (void)in_sizes; (void)n_in; (void)out_size;

    const float* data  = (const float*)d_in[0];
    const float* adj   = (const float*)d_in[2];
    const int*   trans = (const int*)d_in[3];
    const int*   einx  = (const int*)d_in[4];
    const int*   label = (const int*)d_in[5];
    const float* mask  = (const float*)d_in[6];
    const float* w1    = (const float*)d_in[7];
    const float* b1    = (const float*)d_in[8];
    const float* w2    = (const float*)d_in[9];
    const float* b2    = (const float*)d_in[10];
    const float* w21   = (const float*)d_in[11];
    const float* b21   = (const float*)d_in[12];
    const float* w22   = (const float*)d_in[13];
    const float* b22   = (const float*)d_in[14];
    const float* gw1   = (const float*)d_in[15];
    const float* gb1   = (const float*)d_in[16];
    const float* gw2   = (const float*)d_in[17];
    const float* gb2   = (const float*)d_in[18];

    char* W = (char*)d_ws;
    // transient region (dead before gemm_ring on the big3 path)
    short* w1T    = (short*)(W + 0);
    short* w2T    = (short*)(W + 196608);
    short* w21T   = (short*)(W + 1376256);
    short* w22T   = (short*)(W + 1572864);
    short* gw1T   = (short*)(W + 2752512);
    short* estack = (short*)(W + 3932160);
    short* C1s    = (short*)(W + 6029312);
    short* F2s    = (short*)(W + 18612224);
    short* xbuf   = (short*)(W + 31195136);
    int*   src    = (int*)(W + 43499136);

    const bool mid  = (ws_size >= (size_t)140352000);
    const bool big2 = (ws_size >= (size_t)189504000);
    const bool big3 = (ws_size >= (size_t)238656000);

    float* out    = (float*)d_out;
    float* logits = out;
    float* lossp  = out + 16000;
    float* h1     = out + 16001;

    if (big3) {
        short* parts = (short*)(W + 0);
        short* xwT   = (short*)(W + 98304000);
        float* hwbuf = (float*)(W + 110592000);
        short* adjbf = (short*)(W + 110656000);

        // 1) prep + ALL of cvt (LDS-light carrier)
        prep_all<<<8497 + 31250, 256, 0, stream>>>(data, trans, w1, w2, w21, w22, gw1, einx,
                                                   w1T, w2T, w21T, w22T, gw1T, estack, src,
                                                   adj, adjbf, 0, 31250);
        // 2) merged MLPs
        gemm_sel<1><<<dim3(6, 64), 256, 0, stream>>>(estack, w1T, w21T, b1, b21, C1s, 128);
        gemm_sel<0><<<dim3(6, 64), 256, 0, stream>>>(C1s, w2T, w22T, b2, b22, F2s, 768);
        // 3) xwT = gw1^T @ x^T with FUSED gather (B rows = F2s[src[gb]])
        gemm_bf<0, 0, 1, 0, 1><<<dim3(63, 6), 256, 0, stream>>>(
            gw1T, F2s, nullptr, xwT, 768, 8000, 768, 768, 768, 8000, src);
        // 4) big GEMM (r10 ring-4 reg-lookahead) + fused reduce + h1w2
        gemm_ring<<<dim3(3, 32, 8), 512, 0, stream>>>(adjbf, xwT, parts, 8000, 8000, 8000, 8000);
        reduce_h1_hw<<<8000, 192, 0, stream>>>(parts, gb1, gw2, h1, hwbuf, 8);
        // 5) logits + loss
        adj_hw_bf<<<8000, 256, 0, stream>>>(adjbf, hwbuf, gb2, logits);
        loss_kernel<<<1, 256, 0, stream>>>(logits, label, mask, lossp);
        return;
    }

    // ---------- fallback paths (old structure, standalone cvt) ----------
    short* adjbf = (short*)W;
    short* xwT;  float* hwbuf;  short* parts = nullptr;
    if (mid) {
        xwT   = (short*)(W + 128000000);
        hwbuf = (float*)(W + 140288000);
        if (big2) parts = (short*)(W + 140352000);
    } else {
        xwT   = (short*)(W + 48425856);
        hwbuf = (float*)(W + 60713856);
    }

    prep_all<<<8497, 256, 0, stream>>>(data, trans, w1, w2, w21, w22, gw1, einx,
                                       w1T, w2T, w21T, w22T, gw1T, estack, src,
                                       nullptr, nullptr, 0, 0);
    gemm_sel<1><<<dim3(6, 64), 256, 0, stream>>>(estack, w1T, w21T, b1, b21, C1s, 128);
    gemm_sel<0><<<dim3(6, 64), 256, 0, stream>>>(C1s, w2T, w22T, b2, b22, F2s, 768);
    gather_x<<<3000, 256, 0, stream>>>(F2s, src, xbuf);
    gemm_bf<0, 0, 1, 0, 0><<<dim3(63, 6), 256, 0, stream>>>(
        gw1T, xbuf, nullptr, xwT, 768, 8000, 768, 768, 768, 8000, nullptr);

    if (mid) {
        cvt_bf16<<<31250, 256, 0, stream>>>(adj, adjbf, 8000000);
        if (big2) {
            gemm_ring<<<dim3(3, 32, 4), 512, 0, stream>>>(adjbf, xwT, parts, 8000, 8000, 8000, 8000);
            reduce_h1_hw<<<8000, 192, 0, stream>>>(parts, gb1, gw2, h1, hwbuf, 4);
        } else {
            gemm_bf<1, 1, 0, 0, 0><<<dim3(6, 63), 256, 0, stream>>>(adjbf, xwT, gb1, h1,
                8000, 768, 8000, 8000, 8000, 768, nullptr);
            h1w2_kernel<<<2000, 256, 0, stream>>>(h1, gw2, hwbuf);
        }
        adj_hw_bf<<<8000, 256, 0, stream>>>(adjbf, hwbuf, gb2, logits);
    } else {
        gemm_bf<1, 1, 0, 1, 0><<<dim3(6, 63), 256, 0, stream>>>(adj, xwT, gb1, h1,
            8000, 768, 8000, 8000, 8000, 768, nullptr);
        h1w2_kernel<<<2000, 256, 0, stream>>>(h1, gw2, hwbuf);
        adj_hw_f32<<<8000, 256, 0, stream>>>(adj, hwbuf, gb2, logits);
    }
    loss_kernel<<<1, 256, 0, stream>>>(logits, label, mask, lossp);
}